// Round 7
// baseline (210.276 us; speedup 1.0000x reference)
//
#include <hip/hip_runtime.h>
#include <hip/hip_bf16.h>

// Problem constants
#define BB 2
#define NN 2048
#define DDIM 1024
#define HH 16
#define HDD 64

typedef __attribute__((ext_vector_type(8))) short bf16x8;
typedef __attribute__((ext_vector_type(4))) short bf16x4;
typedef __attribute__((ext_vector_type(4))) float f32x4;

__device__ inline ushort f2bf(float x) {
  __hip_bfloat16 h = __float2bfloat16(x);
  ushort u;
  __builtin_memcpy(&u, &h, 2);
  return u;
}
__device__ inline float bf2f(ushort u) {
  unsigned v = (unsigned)u << 16;
  float f;
  __builtin_memcpy(&f, &v, 4);
  return f;
}
// raw v_exp_f32: computes 2^x (1 instr; no libm denorm branches)
__device__ inline float exp2_raw(float x) {
  float r;
  asm("v_exp_f32 %0, %1" : "=v"(r) : "v"(x));
  return r;
}

// async global->LDS, 16B per lane; LDS dest must be wave-uniform-base + lane*16
#define GLOAD_LDS16(g, l)                                                              \
  __builtin_amdgcn_global_load_lds((const __attribute__((address_space(1))) void*)(g), \
                                   (__attribute__((address_space(3))) void*)(l), 16, 0, 0)

// ---------------- fp32 -> bf16 elementwise convert (vectorized) ----------------
__global__ __launch_bounds__(256) void cvt_f32_bf16(const float* __restrict__ in,
                                                    ushort* __restrict__ out, int n4) {
  int i = blockIdx.x * 256 + threadIdx.x;
  if (i >= n4) return;
  float4 a = ((const float4*)in)[i];
  ushort4 o;
  o.x = f2bf(a.x); o.y = f2bf(a.y); o.z = f2bf(a.z); o.w = f2bf(a.w);
  ((ushort4*)out)[i] = o;
}

// ------------- fp32 [R][C] -> bf16 [C][R] transpose+convert (32x32 tiles) -------------
__global__ __launch_bounds__(256) void transpose_cvt(const float* __restrict__ in,
                                                     ushort* __restrict__ out, int R, int C) {
  __shared__ float tile[32][33];
  int bx = blockIdx.x * 32, by = blockIdx.y * 32;
  int tx = threadIdx.x, ty = threadIdx.y;
#pragma unroll
  for (int r = ty; r < 32; r += 8)
    tile[r][tx] = in[(size_t)(by + r) * C + bx + tx];
  __syncthreads();
#pragma unroll
  for (int r = ty; r < 32; r += 8)
    out[(size_t)(bx + r) * R + by + tx] = f2bf(tile[tx][r]);
}

// ---------------- bf16 GEMM: C[M][N] = A[M][K] * Bt[N][K]^T + bias ----------------
// 128x128 tile, BK=32, 4 waves each 64x64, global_load_lds(16B) staging (m97 structure).
// MODE 1: bf16 out. MODE 2: QKV split — cols<2048 -> qk[row][2048],
//         cols>=2048 (the V block) written TRANSPOSED to Vt[bh][d][n] (ushort4 stores).
template <int MODE>
__global__ __launch_bounds__(256) void gemm_bt(const ushort* __restrict__ A,
                                               const ushort* __restrict__ Bt,
                                               const float* __restrict__ bias,
                                               void* __restrict__ Cv,
                                               ushort* __restrict__ Vt,
                                               int M, int N, int K) {
  __shared__ ushort As[128 * 32];
  __shared__ ushort Bs[128 * 32];
  const int tid = threadIdx.x;
  const int wid = tid >> 6, lane = tid & 63;
  const int c = lane & 15, g = lane >> 4;
  const int wm = (wid >> 1) * 64, wn = (wid & 1) * 64;
  const int m0 = blockIdx.y * 128, n0 = blockIdx.x * 128;
  f32x4 acc[4][4] = {};
  for (int k0 = 0; k0 < K; k0 += 32) {
    __syncthreads();
#pragma unroll
    for (int it = 0; it < 2; ++it) {
      int G = tid + it * 256;
      int row = G >> 2, sl = G & 3;
      GLOAD_LDS16(A + (size_t)(m0 + row) * K + k0 + sl * 8, &As[G * 8]);
      GLOAD_LDS16(Bt + (size_t)(n0 + row) * K + k0 + sl * 8, &Bs[G * 8]);
    }
    __syncthreads();
    bf16x8 af[4], bfr[4];
#pragma unroll
    for (int i = 0; i < 4; ++i) {
      af[i] = *(const bf16x8*)(&As[(wm + i * 16 + c) * 32 + g * 8]);
      bfr[i] = *(const bf16x8*)(&Bs[(wn + i * 16 + c) * 32 + g * 8]);
    }
#pragma unroll
    for (int i = 0; i < 4; ++i)
#pragma unroll
      for (int j = 0; j < 4; ++j)
        acc[i][j] = __builtin_amdgcn_mfma_f32_16x16x32_bf16(af[i], bfr[j], acc[i][j], 0, 0, 0);
  }
#pragma unroll
  for (int i = 0; i < 4; ++i) {
#pragma unroll
    for (int j = 0; j < 4; ++j) {
      const int col = n0 + wn + j * 16 + c;
      const float bv = bias[col];
      const int row = m0 + wm + i * 16 + g * 4;
      if (MODE == 2 && col >= 2048) {
        const int hh = (col - 2048) >> 6, dd = (col - 2048) & 63;
        const int bb = row >> 11, nl = row & 2047;
        ushort4 ov;
        ov.x = f2bf(acc[i][j][0] + bv);
        ov.y = f2bf(acc[i][j][1] + bv);
        ov.z = f2bf(acc[i][j][2] + bv);
        ov.w = f2bf(acc[i][j][3] + bv);
        *(ushort4*)(&Vt[(size_t)((bb * 16 + hh) * 64 + dd) * NN + nl]) = ov;
      } else {
        const int ldc = (MODE == 2) ? 2048 : N;
#pragma unroll
        for (int ri = 0; ri < 4; ++ri) {
          float v = acc[i][j][ri] + bv;
          ((ushort*)Cv)[(size_t)(row + ri) * ldc + col] = f2bf(v);
        }
      }
    }
  }
}

// ---------------- proj GEMM (float out), 64x128 tile for 2 blocks/CU occupancy ------
__global__ __launch_bounds__(256) void gemm_proj(const ushort* __restrict__ A,
                                                 const ushort* __restrict__ Bt,
                                                 const float* __restrict__ bias,
                                                 float* __restrict__ C, int M, int N, int K) {
  __shared__ ushort As[64 * 32];
  __shared__ ushort Bs[128 * 32];
  const int tid = threadIdx.x;
  const int wid = tid >> 6, lane = tid & 63;
  const int c = lane & 15, g = lane >> 4;
  const int wn = wid * 32;
  const int m0 = blockIdx.y * 64, n0 = blockIdx.x * 128;
  f32x4 acc[4][2] = {};
  for (int k0 = 0; k0 < K; k0 += 32) {
    __syncthreads();
#pragma unroll
    for (int it = 0; it < 3; ++it) {
      int G = tid + it * 256;
      if (G < 256) {
        int row = G >> 2, sl = G & 3;
        GLOAD_LDS16(A + (size_t)(m0 + row) * K + k0 + sl * 8, &As[G * 8]);
      } else {
        int GB = G - 256;
        int row = GB >> 2, sl = GB & 3;
        GLOAD_LDS16(Bt + (size_t)(n0 + row) * K + k0 + sl * 8, &Bs[GB * 8]);
      }
    }
    __syncthreads();
    bf16x8 af[4], bfr[2];
#pragma unroll
    for (int i = 0; i < 4; ++i) af[i] = *(const bf16x8*)(&As[(i * 16 + c) * 32 + g * 8]);
#pragma unroll
    for (int j = 0; j < 2; ++j)
      bfr[j] = *(const bf16x8*)(&Bs[(wn + j * 16 + c) * 32 + g * 8]);
#pragma unroll
    for (int i = 0; i < 4; ++i)
#pragma unroll
      for (int j = 0; j < 2; ++j)
        acc[i][j] = __builtin_amdgcn_mfma_f32_16x16x32_bf16(af[i], bfr[j], acc[i][j], 0, 0, 0);
  }
#pragma unroll
  for (int i = 0; i < 4; ++i) {
#pragma unroll
    for (int j = 0; j < 2; ++j) {
      const int col = n0 + wn + j * 16 + c;
      const float bv = bias[col];
      const int row = m0 + i * 16 + g * 4;
#pragma unroll
      for (int ri = 0; ri < 4; ++ri)
        C[(size_t)(row + ri) * N + col] = acc[i][j][ri] + bv;
    }
  }
}

// ---------------- causal flash attention (QBLK=128: 2 q-frags/wave) ----------------
// QK: [B*N][2048] bf16. Vt: [B*H][64][N] bf16. grid (B*H=32, N/128=16), heavy first.
// Wave w owns q-rows {qb*128+w*16..+15} (qr=0) and {qb*128+64+w*16..+15} (qr=1).
// K/V tile staged ONCE serves both q-frags: LDS reads, barriers, staging amortized 2x.
// qfrag qr diagonal-masked iff t == 2*qb+qr; qfrag0 inactive only at t==2*qb+1.
__global__ __launch_bounds__(256) void attn_fwd(const ushort* __restrict__ QK,
                                                const ushort* __restrict__ Vt,
                                                ushort* __restrict__ O) {
  const int bh = blockIdx.x;
  const int b = bh >> 4, h = bh & 15;
  const int qb = (int)gridDim.y - 1 - (int)blockIdx.y;
  const int tid = threadIdx.x;
  const int wid = tid >> 6, lane = tid & 63;
  const int c = lane & 15, g = lane >> 4;
  const int q0 = qb * 128 + wid * 16;
  const ushort* Qb = QK + (size_t)b * NN * 2048 + (size_t)h * HDD;
  const ushort* Kb = Qb + 1024;
  const ushort* Vb = Vt + (size_t)bh * HDD * NN;

  __shared__ ushort Ks[2][64 * 64];  // linear [row][slot*8]; content XOR-swizzled via src
  __shared__ ushort Vs[2][64 * 64];

  // Q fragments (2 q-frags), pre-scaled by 0.125 * log2(e)
  const float SC = 0.18033688011112042f;
  bf16x8 qf[2][2];
#pragma unroll
  for (int qr = 0; qr < 2; ++qr) {
    const ushort* qrow = Qb + (size_t)(q0 + qr * 64 + c) * 2048 + g * 8;
    qf[qr][0] = *(const bf16x8*)(qrow);
    qf[qr][1] = *(const bf16x8*)(qrow + 32);
#pragma unroll
    for (int r = 0; r < 2; ++r)
#pragma unroll
      for (int e = 0; e < 8; ++e)
        qf[qr][r][e] = (short)f2bf(bf2f((ushort)qf[qr][r][e]) * SC);
  }

  f32x4 oacc[2][4] = {};  // per qfrag: O^T[d = 16db + 4g + i][qrow+c]
  float m[2] = {0.f, 0.f}, lsum[2] = {0.f, 0.f};
  const int q_abs[2] = {q0 + c, q0 + 64 + c};

#define STAGE_TILE(kv0, bufi)                                                   \
  do {                                                                          \
    _Pragma("unroll") for (int it = 0; it < 2; ++it) {                          \
      int u = tid + it * 256;                                                   \
      int row = u >> 3, sl = u & 7;                                             \
      int ksl = (sl ^ (row & 7)) * 8;                                           \
      GLOAD_LDS16(Kb + (size_t)((kv0) + row) * 2048 + ksl, &Ks[bufi][u * 8]);   \
      GLOAD_LDS16(Vb + (size_t)row * NN + (kv0) + ksl, &Vs[bufi][u * 8]);       \
    }                                                                           \
  } while (0)

  STAGE_TILE(0, 0);
  __syncthreads();
  int cur = 0;
  const int ntiles = 2 * qb + 2;

  for (int t = 0; t < ntiles; ++t) {
    if (t < ntiles - 1) STAGE_TILE((t + 1) * 64, cur ^ 1);  // prefetch overlaps compute
    const bool act0 = (t <= 2 * qb);  // qfrag0 active? (block-uniform)

    // S^T for both q-frags, sharing kf LDS reads
    f32x4 s[2][4] = {};
#pragma unroll
    for (int f = 0; f < 4; ++f) {
      int krow = f * 16 + c;
#pragma unroll
      for (int dc = 0; dc < 2; ++dc) {
        int slot = (dc * 4 + g) ^ (krow & 7);
        bf16x8 kf = *(const bf16x8*)(&Ks[cur][krow * 64 + slot * 8]);
        if (act0) s[0][f] = __builtin_amdgcn_mfma_f32_16x16x32_bf16(kf, qf[0][dc], s[0][f], 0, 0, 0);
        s[1][f] = __builtin_amdgcn_mfma_f32_16x16x32_bf16(kf, qf[1][dc], s[1][f], 0, 0, 0);
      }
    }

    // online softmax per q-frag (log2 domain, defer-max)
    bf16x4 pb[2][4];
#pragma unroll
    for (int qr = 0; qr < 2; ++qr) {
      if (qr == 0 && !act0) continue;
      float pmax = -INFINITY;
      if (t == 2 * qb + qr) {  // diagonal tile for this q-frag
        const int kv0 = t * 64;
#pragma unroll
        for (int f = 0; f < 4; ++f)
#pragma unroll
          for (int i = 0; i < 4; ++i) {
            if (kv0 + f * 16 + g * 4 + i > q_abs[qr]) s[qr][f][i] = -INFINITY;
            pmax = fmaxf(pmax, s[qr][f][i]);
          }
      } else {
#pragma unroll
        for (int f = 0; f < 4; ++f)
#pragma unroll
          for (int i = 0; i < 4; ++i) pmax = fmaxf(pmax, s[qr][f][i]);
      }
      if (t == 0) {
        float pr = fmaxf(pmax, __shfl_xor(pmax, 16));
        pr = fmaxf(pr, __shfl_xor(pr, 32));
        m[qr] = pr;
      } else if (!__all(pmax <= m[qr] + 8.f)) {
        float pr = fmaxf(pmax, __shfl_xor(pmax, 16));
        pr = fmaxf(pr, __shfl_xor(pr, 32));
        float mnew = fmaxf(m[qr], pr);
        float corr = exp2_raw(m[qr] - mnew);
        lsum[qr] *= corr;
#pragma unroll
        for (int db = 0; db < 4; ++db) {
          oacc[qr][db][0] *= corr; oacc[qr][db][1] *= corr;
          oacc[qr][db][2] *= corr; oacc[qr][db][3] *= corr;
        }
        m[qr] = mnew;
      }
      float psum = 0.f;
#pragma unroll
      for (int f = 0; f < 4; ++f) {
#pragma unroll
        for (int i = 0; i < 4; ++i) {
          float p = exp2_raw(s[qr][f][i] - m[qr]);
          s[qr][f][i] = p;
          psum += p;
        }
        pb[qr][f][0] = (short)f2bf(s[qr][f][0]);
        pb[qr][f][1] = (short)f2bf(s[qr][f][1]);
        pb[qr][f][2] = (short)f2bf(s[qr][f][2]);
        pb[qr][f][3] = (short)f2bf(s[qr][f][3]);
      }
      lsum[qr] += psum;
    }

    // PV for both q-frags, sharing vf LDS reads
#pragma unroll
    for (int f = 0; f < 4; ++f) {
      const int slot = f * 2 + (g >> 1);
#pragma unroll
      for (int db = 0; db < 4; ++db) {
        int d = db * 16 + c;
        bf16x4 vf =
            *(const bf16x4*)(&Vs[cur][d * 64 + ((slot ^ (d & 7)) * 8) + (g & 1) * 4]);
        if (act0)
          oacc[0][db] = __builtin_amdgcn_mfma_f32_16x16x16bf16_1k(vf, pb[0][f], oacc[0][db], 0, 0, 0);
        oacc[1][db] = __builtin_amdgcn_mfma_f32_16x16x16bf16_1k(vf, pb[1][f], oacc[1][db], 0, 0, 0);
      }
    }
    __syncthreads();  // drains prefetch vmcnt + releases cur buffer
    cur ^= 1;
  }

#pragma unroll
  for (int qr = 0; qr < 2; ++qr) {
    float l = lsum[qr];
    l += __shfl_xor(l, 16);
    l += __shfl_xor(l, 32);
    float invl = 1.f / l;
    ushort* orow = O + (size_t)(b * NN + q0 + qr * 64 + c) * DDIM + h * HDD;
#pragma unroll
    for (int db = 0; db < 4; ++db) {
      ushort4 ov;
      ov.x = f2bf(oacc[qr][db][0] * invl);
      ov.y = f2bf(oacc[qr][db][1] * invl);
      ov.z = f2bf(oacc[qr][db][2] * invl);
      ov.w = f2bf(oacc[qr][db][3] * invl);
      *(ushort4*)(&orow[db * 16 + g * 4]) = ov;
    }
  }
}

extern "C" void kernel_launch(void* const* d_in, const int* in_sizes, int n_in,
                              void* d_out, int out_size, void* d_ws, size_t ws_size,
                              hipStream_t stream) {
  const float* hidden = (const float*)d_in[0];  // [B,N,D]
  const float* W_attn = (const float*)d_in[1];  // [D,3D]
  const float* b_attn = (const float*)d_in[2];  // [3D]
  const float* W_proj = (const float*)d_in[3];  // [D,D]
  const float* b_proj = (const float*)d_in[4];  // [D]

  char* ws = (char*)d_ws;
  ushort* hbf  = (ushort*)(ws);                       // 8 MB  hidden bf16 [4096][1024]
  ushort* WaT  = (ushort*)(ws + (size_t)(8 << 20));   // 6 MB  W_attn^T bf16 [3072][1024]
  ushort* WpT  = (ushort*)(ws + (size_t)(14 << 20));  // 2 MB  W_proj^T bf16 [1024][1024]
  ushort* qk   = (ushort*)(ws + (size_t)(16 << 20));  // 16 MB Q|K bf16 [4096][2048]
  ushort* vt   = (ushort*)(ws + (size_t)(32 << 20));  // 8 MB  V^T bf16 [32][64][2048]
  ushort* aout = (ushort*)(ws + (size_t)(40 << 20));  // 8 MB  attn out bf16 [4096][1024]

  cvt_f32_bf16<<<4096, 256, 0, stream>>>(hidden, hbf, (BB * NN * DDIM) / 4);
  transpose_cvt<<<dim3(96, 32), dim3(32, 8), 0, stream>>>(W_attn, WaT, 1024, 3072);
  transpose_cvt<<<dim3(32, 32), dim3(32, 8), 0, stream>>>(W_proj, WpT, 1024, 1024);

  gemm_bt<2><<<dim3(24, 32), 256, 0, stream>>>(hbf, WaT, b_attn, qk, vt, 4096, 3072, 1024);
  attn_fwd<<<dim3(32, 16), 256, 0, stream>>>(qk, vt, aout);
  gemm_proj<<<dim3(8, 64), 256, 0, stream>>>(aout, WpT, b_proj, (float*)d_out, 4096, 1024, 1024);
}

// Round 8
// 197.726 us; speedup vs baseline: 1.0635x; 1.0635x over previous
//
#include <hip/hip_runtime.h>
#include <hip/hip_bf16.h>

// Problem constants
#define BB 2
#define NN 2048
#define DDIM 1024
#define HH 16
#define HDD 64

typedef __attribute__((ext_vector_type(8))) short bf16x8;
typedef __attribute__((ext_vector_type(4))) short bf16x4;
typedef __attribute__((ext_vector_type(4))) float f32x4;

__device__ inline ushort f2bf(float x) {
  __hip_bfloat16 h = __float2bfloat16(x);
  ushort u;
  __builtin_memcpy(&u, &h, 2);
  return u;
}
__device__ inline float bf2f(ushort u) {
  unsigned v = (unsigned)u << 16;
  float f;
  __builtin_memcpy(&f, &v, 4);
  return f;
}
// raw v_exp_f32: computes 2^x (1 instr; no libm denorm branches)
__device__ inline float exp2_raw(float x) {
  float r;
  asm("v_exp_f32 %0, %1" : "=v"(r) : "v"(x));
  return r;
}

// async global->LDS, 16B per lane; LDS dest must be wave-uniform-base + lane*16
#define GLOAD_LDS16(g, l)                                                              \
  __builtin_amdgcn_global_load_lds((const __attribute__((address_space(1))) void*)(g), \
                                   (__attribute__((address_space(3))) void*)(l), 16, 0, 0)

// ---------------- fp32 -> bf16 elementwise convert (vectorized) ----------------
__global__ __launch_bounds__(256) void cvt_f32_bf16(const float* __restrict__ in,
                                                    ushort* __restrict__ out, int n4) {
  int i = blockIdx.x * 256 + threadIdx.x;
  if (i >= n4) return;
  float4 a = ((const float4*)in)[i];
  ushort4 o;
  o.x = f2bf(a.x); o.y = f2bf(a.y); o.z = f2bf(a.z); o.w = f2bf(a.w);
  ((ushort4*)out)[i] = o;
}

// ------------- fp32 [R][C] -> bf16 [C][R] transpose+convert (32x32 tiles) -------------
__global__ __launch_bounds__(256) void transpose_cvt(const float* __restrict__ in,
                                                     ushort* __restrict__ out, int R, int C) {
  __shared__ float tile[32][33];
  int bx = blockIdx.x * 32, by = blockIdx.y * 32;
  int tx = threadIdx.x, ty = threadIdx.y;
#pragma unroll
  for (int r = ty; r < 32; r += 8)
    tile[r][tx] = in[(size_t)(by + r) * C + bx + tx];
  __syncthreads();
#pragma unroll
  for (int r = ty; r < 32; r += 8)
    out[(size_t)(bx + r) * R + by + tx] = f2bf(tile[tx][r]);
}

// ---------------- bf16 GEMM: C[M][N] = A[M][K] * Bt[N][K]^T + bias ----------------
// 128x128 tile, BK=32, 4 waves each 64x64, global_load_lds(16B) staging (m97 structure).
// MODE 2: QKV split — cols<2048 -> qk[row][2048], cols>=2048 (V) transposed to Vt.
template <int MODE>
__global__ __launch_bounds__(256) void gemm_bt(const ushort* __restrict__ A,
                                               const ushort* __restrict__ Bt,
                                               const float* __restrict__ bias,
                                               void* __restrict__ Cv,
                                               ushort* __restrict__ Vt,
                                               int M, int N, int K) {
  __shared__ ushort As[128 * 32];
  __shared__ ushort Bs[128 * 32];
  const int tid = threadIdx.x;
  const int wid = tid >> 6, lane = tid & 63;
  const int c = lane & 15, g = lane >> 4;
  const int wm = (wid >> 1) * 64, wn = (wid & 1) * 64;
  const int m0 = blockIdx.y * 128, n0 = blockIdx.x * 128;
  f32x4 acc[4][4] = {};
  for (int k0 = 0; k0 < K; k0 += 32) {
    __syncthreads();
#pragma unroll
    for (int it = 0; it < 2; ++it) {
      int G = tid + it * 256;
      int row = G >> 2, sl = G & 3;
      GLOAD_LDS16(A + (size_t)(m0 + row) * K + k0 + sl * 8, &As[G * 8]);
      GLOAD_LDS16(Bt + (size_t)(n0 + row) * K + k0 + sl * 8, &Bs[G * 8]);
    }
    __syncthreads();
    bf16x8 af[4], bfr[4];
#pragma unroll
    for (int i = 0; i < 4; ++i) {
      af[i] = *(const bf16x8*)(&As[(wm + i * 16 + c) * 32 + g * 8]);
      bfr[i] = *(const bf16x8*)(&Bs[(wn + i * 16 + c) * 32 + g * 8]);
    }
#pragma unroll
    for (int i = 0; i < 4; ++i)
#pragma unroll
      for (int j = 0; j < 4; ++j)
        acc[i][j] = __builtin_amdgcn_mfma_f32_16x16x32_bf16(af[i], bfr[j], acc[i][j], 0, 0, 0);
  }
#pragma unroll
  for (int i = 0; i < 4; ++i) {
#pragma unroll
    for (int j = 0; j < 4; ++j) {
      const int col = n0 + wn + j * 16 + c;
      const float bv = bias[col];
      const int row = m0 + wm + i * 16 + g * 4;
      if (MODE == 2 && col >= 2048) {
        const int hh = (col - 2048) >> 6, dd = (col - 2048) & 63;
        const int bb = row >> 11, nl = row & 2047;
        ushort4 ov;
        ov.x = f2bf(acc[i][j][0] + bv);
        ov.y = f2bf(acc[i][j][1] + bv);
        ov.z = f2bf(acc[i][j][2] + bv);
        ov.w = f2bf(acc[i][j][3] + bv);
        *(ushort4*)(&Vt[(size_t)((bb * 16 + hh) * 64 + dd) * NN + nl]) = ov;
      } else {
        const int ldc = (MODE == 2) ? 2048 : N;
#pragma unroll
        for (int ri = 0; ri < 4; ++ri) {
          float v = acc[i][j][ri] + bv;
          ((ushort*)Cv)[(size_t)(row + ri) * ldc + col] = f2bf(v);
        }
      }
    }
  }
}

// ---------------- proj GEMM (float out), 64x128 tile for 2 blocks/CU occupancy ------
__global__ __launch_bounds__(256) void gemm_proj(const ushort* __restrict__ A,
                                                 const ushort* __restrict__ Bt,
                                                 const float* __restrict__ bias,
                                                 float* __restrict__ C, int M, int N, int K) {
  __shared__ ushort As[64 * 32];
  __shared__ ushort Bs[128 * 32];
  const int tid = threadIdx.x;
  const int wid = tid >> 6, lane = tid & 63;
  const int c = lane & 15, g = lane >> 4;
  const int wn = wid * 32;
  const int m0 = blockIdx.y * 64, n0 = blockIdx.x * 128;
  f32x4 acc[4][2] = {};
  for (int k0 = 0; k0 < K; k0 += 32) {
    __syncthreads();
#pragma unroll
    for (int it = 0; it < 3; ++it) {
      int G = tid + it * 256;
      if (G < 256) {
        int row = G >> 2, sl = G & 3;
        GLOAD_LDS16(A + (size_t)(m0 + row) * K + k0 + sl * 8, &As[G * 8]);
      } else {
        int GB = G - 256;
        int row = GB >> 2, sl = GB & 3;
        GLOAD_LDS16(Bt + (size_t)(n0 + row) * K + k0 + sl * 8, &Bs[GB * 8]);
      }
    }
    __syncthreads();
    bf16x8 af[4], bfr[2];
#pragma unroll
    for (int i = 0; i < 4; ++i) af[i] = *(const bf16x8*)(&As[(i * 16 + c) * 32 + g * 8]);
#pragma unroll
    for (int j = 0; j < 2; ++j)
      bfr[j] = *(const bf16x8*)(&Bs[(wn + j * 16 + c) * 32 + g * 8]);
#pragma unroll
    for (int i = 0; i < 4; ++i)
#pragma unroll
      for (int j = 0; j < 2; ++j)
        acc[i][j] = __builtin_amdgcn_mfma_f32_16x16x32_bf16(af[i], bfr[j], acc[i][j], 0, 0, 0);
  }
#pragma unroll
  for (int i = 0; i < 4; ++i) {
#pragma unroll
    for (int j = 0; j < 2; ++j) {
      const int col = n0 + wn + j * 16 + c;
      const float bv = bias[col];
      const int row = m0 + i * 16 + g * 4;
#pragma unroll
      for (int ri = 0; ri < 4; ++ri)
        C[(size_t)(row + ri) * N + col] = acc[i][j][ri] + bv;
    }
  }
}

// ---------------- causal flash attention (QBLK=128, 8 waves, 1 q-frag/wave) ---------
// QK: [B*N][2048] bf16. Vt: [B*H][64][N] bf16. grid (B*H=32, N/128=16), heavy first.
// 512 threads = 8 waves; wave w owns q-rows qb*128 + w*16 .. +15. One K/V stage per
// tile-step serves all 8 waves (2x amortization vs 4-wave QBLK=64) while keeping
// 512 blocks x 8 waves = 4096 waves (the R6 occupancy-collapse fix).
// S^T = mfma16x16x32(K, Q); PV = mfma16x16x16(V^T, P^T), P stays in-register.
__global__ __launch_bounds__(512) void attn_fwd(const ushort* __restrict__ QK,
                                                const ushort* __restrict__ Vt,
                                                ushort* __restrict__ O) {
  const int bh = blockIdx.x;
  const int b = bh >> 4, h = bh & 15;
  const int qb = (int)gridDim.y - 1 - (int)blockIdx.y;
  const int tid = threadIdx.x;
  const int wid = tid >> 6, lane = tid & 63;
  const int c = lane & 15, g = lane >> 4;
  const int q0 = qb * 128 + wid * 16;
  const ushort* Qb = QK + (size_t)b * NN * 2048 + (size_t)h * HDD;
  const ushort* Kb = Qb + 1024;
  const ushort* Vb = Vt + (size_t)bh * HDD * NN;

  __shared__ ushort Ks[2][64 * 64];  // linear [row][slot*8]; content XOR-swizzled via src
  __shared__ ushort Vs[2][64 * 64];

  // Q fragment, pre-scaled by 0.125 * log2(e)
  const float SC = 0.18033688011112042f;
  bf16x8 qf[2];
  {
    const ushort* qrow = Qb + (size_t)(q0 + c) * 2048 + g * 8;
    qf[0] = *(const bf16x8*)(qrow);
    qf[1] = *(const bf16x8*)(qrow + 32);
#pragma unroll
    for (int r = 0; r < 2; ++r)
#pragma unroll
      for (int e = 0; e < 8; ++e) qf[r][e] = (short)f2bf(bf2f((ushort)qf[r][e]) * SC);
  }

  f32x4 oacc[4] = {};  // O^T[d = 16db + 4g + i][q0+c]
  float m = 0.f, lsum = 0.f;  // m in log2 domain
  const int q_abs = q0 + c;
  const int tdiag = 2 * qb + (wid >> 2);  // this wave's diagonal tile

  // 512 threads stage one 64x64 K tile + one 64x64 V^T tile (1 granule each/thread)
#define STAGE_TILE(kv0, bufi)                                                   \
  do {                                                                          \
    int u = tid;                                                                \
    int row = u >> 3, sl = u & 7;                                               \
    int ksl = (sl ^ (row & 7)) * 8;                                             \
    GLOAD_LDS16(Kb + (size_t)((kv0) + row) * 2048 + ksl, &Ks[bufi][u * 8]);     \
    GLOAD_LDS16(Vb + (size_t)row * NN + (kv0) + ksl, &Vs[bufi][u * 8]);         \
  } while (0)

  STAGE_TILE(0, 0);
  __syncthreads();
  int cur = 0;
  const int ntiles = 2 * qb + 2;

  for (int t = 0; t < ntiles; ++t) {
    if (t < ntiles - 1) STAGE_TILE((t + 1) * 64, cur ^ 1);  // prefetch overlaps compute

    if (t <= tdiag) {  // wave-uniform activity gate
      // S^T: 4 kv-frags x 2 d-chunks of 32 (values already log2-scaled via Q)
      f32x4 s[4] = {};
#pragma unroll
      for (int f = 0; f < 4; ++f) {
        int krow = f * 16 + c;
#pragma unroll
        for (int dc = 0; dc < 2; ++dc) {
          int slot = (dc * 4 + g) ^ (krow & 7);
          bf16x8 kf = *(const bf16x8*)(&Ks[cur][krow * 64 + slot * 8]);
          s[f] = __builtin_amdgcn_mfma_f32_16x16x32_bf16(kf, qf[dc], s[f], 0, 0, 0);
        }
      }

      // local max (mask only on this wave's diagonal tile; wave-uniform branch)
      float pmax = -INFINITY;
      if (t == tdiag) {
        const int kv0 = t * 64;
#pragma unroll
        for (int f = 0; f < 4; ++f)
#pragma unroll
          for (int i = 0; i < 4; ++i) {
            if (kv0 + f * 16 + g * 4 + i > q_abs) s[f][i] = -INFINITY;
            pmax = fmaxf(pmax, s[f][i]);
          }
      } else {
#pragma unroll
        for (int f = 0; f < 4; ++f)
#pragma unroll
          for (int i = 0; i < 4; ++i) pmax = fmaxf(pmax, s[f][i]);
      }

      // defer-max: full cross-lane reduce + rescale only when needed
      if (t == 0) {
        float pr = fmaxf(pmax, __shfl_xor(pmax, 16));
        pr = fmaxf(pr, __shfl_xor(pr, 32));
        m = pr;
      } else if (!__all(pmax <= m + 8.f)) {
        float pr = fmaxf(pmax, __shfl_xor(pmax, 16));
        pr = fmaxf(pr, __shfl_xor(pr, 32));
        float mnew = fmaxf(m, pr);
        float corr = exp2_raw(m - mnew);
        lsum *= corr;
#pragma unroll
        for (int db = 0; db < 4; ++db) {
          oacc[db][0] *= corr; oacc[db][1] *= corr;
          oacc[db][2] *= corr; oacc[db][3] *= corr;
        }
        m = mnew;
      }

      float psum = 0.f;
#pragma unroll
      for (int f = 0; f < 4; ++f)
#pragma unroll
        for (int i = 0; i < 4; ++i) {
          float p = exp2_raw(s[f][i] - m);
          s[f][i] = p;
          psum += p;
        }
      lsum += psum;  // lane-local partial; cross-g reduce deferred to epilogue

      // PV: O^T += V^T * P^T  (K=16 chunks over f)
#pragma unroll
      for (int f = 0; f < 4; ++f) {
        bf16x4 pb;
        pb[0] = (short)f2bf(s[f][0]);
        pb[1] = (short)f2bf(s[f][1]);
        pb[2] = (short)f2bf(s[f][2]);
        pb[3] = (short)f2bf(s[f][3]);
        const int slot = f * 2 + (g >> 1);
#pragma unroll
        for (int db = 0; db < 4; ++db) {
          int d = db * 16 + c;
          bf16x4 vf =
              *(const bf16x4*)(&Vs[cur][d * 64 + ((slot ^ (d & 7)) * 8) + (g & 1) * 4]);
          oacc[db] = __builtin_amdgcn_mfma_f32_16x16x16bf16_1k(vf, pb, oacc[db], 0, 0, 0);
        }
      }
    }
    __syncthreads();  // drains prefetch vmcnt + releases cur buffer
    cur ^= 1;
  }

  lsum += __shfl_xor(lsum, 16);
  lsum += __shfl_xor(lsum, 32);
  float invl = 1.f / lsum;
  ushort* orow = O + (size_t)(b * NN + q0 + c) * DDIM + h * HDD;
#pragma unroll
  for (int db = 0; db < 4; ++db) {
    ushort4 ov;
    ov.x = f2bf(oacc[db][0] * invl);
    ov.y = f2bf(oacc[db][1] * invl);
    ov.z = f2bf(oacc[db][2] * invl);
    ov.w = f2bf(oacc[db][3] * invl);
    *(ushort4*)(&orow[db * 16 + g * 4]) = ov;
  }
}

extern "C" void kernel_launch(void* const* d_in, const int* in_sizes, int n_in,
                              void* d_out, int out_size, void* d_ws, size_t ws_size,
                              hipStream_t stream) {
  const float* hidden = (const float*)d_in[0];  // [B,N,D]
  const float* W_attn = (const float*)d_in[1];  // [D,3D]
  const float* b_attn = (const float*)d_in[2];  // [3D]
  const float* W_proj = (const float*)d_in[3];  // [D,D]
  const float* b_proj = (const float*)d_in[4];  // [D]

  char* ws = (char*)d_ws;
  ushort* hbf  = (ushort*)(ws);                       // 8 MB  hidden bf16 [4096][1024]
  ushort* WaT  = (ushort*)(ws + (size_t)(8 << 20));   // 6 MB  W_attn^T bf16 [3072][1024]
  ushort* WpT  = (ushort*)(ws + (size_t)(14 << 20));  // 2 MB  W_proj^T bf16 [1024][1024]
  ushort* qk   = (ushort*)(ws + (size_t)(16 << 20));  // 16 MB Q|K bf16 [4096][2048]
  ushort* vt   = (ushort*)(ws + (size_t)(32 << 20));  // 8 MB  V^T bf16 [32][64][2048]
  ushort* aout = (ushort*)(ws + (size_t)(40 << 20));  // 8 MB  attn out bf16 [4096][1024]

  cvt_f32_bf16<<<4096, 256, 0, stream>>>(hidden, hbf, (BB * NN * DDIM) / 4);
  transpose_cvt<<<dim3(96, 32), dim3(32, 8), 0, stream>>>(W_attn, WaT, 1024, 3072);
  transpose_cvt<<<dim3(32, 32), dim3(32, 8), 0, stream>>>(W_proj, WpT, 1024, 1024);

  gemm_bt<2><<<dim3(24, 32), 256, 0, stream>>>(hbf, WaT, b_attn, qk, vt, 4096, 3072, 1024);
  attn_fwd<<<dim3(32, 16), 512, 0, stream>>>(qk, vt, aout);
  gemm_proj<<<dim3(8, 64), 256, 0, stream>>>(aout, WpT, b_proj, (float*)d_out, 4096, 1024, 1024);
}

// Round 9
// 191.593 us; speedup vs baseline: 1.0975x; 1.0320x over previous
//
#include <hip/hip_runtime.h>
#include <hip/hip_bf16.h>

// Problem constants
#define BB 2
#define NN 2048
#define DDIM 1024
#define HH 16
#define HDD 64

typedef __attribute__((ext_vector_type(8))) short bf16x8;
typedef __attribute__((ext_vector_type(4))) short bf16x4;
typedef __attribute__((ext_vector_type(4))) float f32x4;

__device__ inline ushort f2bf(float x) {
  __hip_bfloat16 h = __float2bfloat16(x);
  ushort u;
  __builtin_memcpy(&u, &h, 2);
  return u;
}
__device__ inline float bf2f(ushort u) {
  unsigned v = (unsigned)u << 16;
  float f;
  __builtin_memcpy(&f, &v, 4);
  return f;
}
// raw v_exp_f32: computes 2^x
__device__ inline float exp2_raw(float x) {
  float r;
  asm("v_exp_f32 %0, %1" : "=v"(r) : "v"(x));
  return r;
}

// async global->LDS, 16B per lane; LDS dest must be wave-uniform-base + lane*16
#define GLOAD_LDS16(g, l)                                                              \
  __builtin_amdgcn_global_load_lds((const __attribute__((address_space(1))) void*)(g), \
                                   (__attribute__((address_space(3))) void*)(l), 16, 0, 0)

// ---------------- fused prep: hidden cvt + W_attn^T + W_proj^T (one launch) ---------
__global__ __launch_bounds__(256) void prep(const float* __restrict__ hidden,
                                            const float* __restrict__ W_attn,
                                            const float* __restrict__ W_proj,
                                            ushort* __restrict__ hbf,
                                            ushort* __restrict__ WaT,
                                            ushort* __restrict__ WpT) {
  __shared__ float tile[32][33];
  const int bid = blockIdx.x, tid = threadIdx.x;
  if (bid < 2048) {  // segment A: fp32 -> bf16 convert of hidden (2 float4 / thread)
    int i = bid * 256 + tid;
    const float4* in4 = (const float4*)hidden;
#pragma unroll
    for (int r = 0; r < 2; ++r, i += 524288) {
      float4 a = in4[i];
      ushort4 o;
      o.x = f2bf(a.x); o.y = f2bf(a.y); o.z = f2bf(a.z); o.w = f2bf(a.w);
      ((ushort4*)hbf)[i] = o;
    }
    return;
  }
  // transpose segments (32x32 tiles, 32x8 thread layout)
  const float* in;
  ushort* out;
  int R, C, bx, by;
  if (bid < 2048 + 3072) {  // W_attn [1024][3072] -> WaT [3072][1024]
    int b2 = bid - 2048;
    in = W_attn; out = WaT; R = 1024; C = 3072;
    bx = (b2 % 96) * 32; by = (b2 / 96) * 32;
  } else {  // W_proj [1024][1024] -> WpT [1024][1024]
    int b3 = bid - 2048 - 3072;
    in = W_proj; out = WpT; R = 1024; C = 1024;
    bx = (b3 & 31) * 32; by = (b3 >> 5) * 32;
  }
  const int tx = tid & 31, ty = tid >> 5;
#pragma unroll
  for (int r = ty; r < 32; r += 8)
    tile[r][tx] = in[(size_t)(by + r) * C + bx + tx];
  __syncthreads();
#pragma unroll
  for (int r = ty; r < 32; r += 8)
    out[(size_t)(bx + r) * R + by + tx] = f2bf(tile[tx][r]);
}

// ---------------- bf16 GEMM: C[M][N] = A[M][K] * Bt[N][K]^T + bias ----------------
// 128x128 tile, BK=32, 4 waves each 64x64, global_load_lds(16B) staging (m97 structure).
// MODE 2: QKV split — cols<2048 -> qk[row][2048], cols>=2048 (V) transposed to Vt.
template <int MODE>
__global__ __launch_bounds__(256) void gemm_bt(const ushort* __restrict__ A,
                                               const ushort* __restrict__ Bt,
                                               const float* __restrict__ bias,
                                               void* __restrict__ Cv,
                                               ushort* __restrict__ Vt,
                                               int M, int N, int K) {
  __shared__ ushort As[128 * 32];
  __shared__ ushort Bs[128 * 32];
  const int tid = threadIdx.x;
  const int wid = tid >> 6, lane = tid & 63;
  const int c = lane & 15, g = lane >> 4;
  const int wm = (wid >> 1) * 64, wn = (wid & 1) * 64;
  const int m0 = blockIdx.y * 128, n0 = blockIdx.x * 128;
  f32x4 acc[4][4] = {};
  for (int k0 = 0; k0 < K; k0 += 32) {
    __syncthreads();
#pragma unroll
    for (int it = 0; it < 2; ++it) {
      int G = tid + it * 256;
      int row = G >> 2, sl = G & 3;
      GLOAD_LDS16(A + (size_t)(m0 + row) * K + k0 + sl * 8, &As[G * 8]);
      GLOAD_LDS16(Bt + (size_t)(n0 + row) * K + k0 + sl * 8, &Bs[G * 8]);
    }
    __syncthreads();
    bf16x8 af[4], bfr[4];
#pragma unroll
    for (int i = 0; i < 4; ++i) {
      af[i] = *(const bf16x8*)(&As[(wm + i * 16 + c) * 32 + g * 8]);
      bfr[i] = *(const bf16x8*)(&Bs[(wn + i * 16 + c) * 32 + g * 8]);
    }
#pragma unroll
    for (int i = 0; i < 4; ++i)
#pragma unroll
      for (int j = 0; j < 4; ++j)
        acc[i][j] = __builtin_amdgcn_mfma_f32_16x16x32_bf16(af[i], bfr[j], acc[i][j], 0, 0, 0);
  }
#pragma unroll
  for (int i = 0; i < 4; ++i) {
#pragma unroll
    for (int j = 0; j < 4; ++j) {
      const int col = n0 + wn + j * 16 + c;
      const float bv = bias[col];
      const int row = m0 + wm + i * 16 + g * 4;
      if (MODE == 2 && col >= 2048) {
        const int hh = (col - 2048) >> 6, dd = (col - 2048) & 63;
        const int bb = row >> 11, nl = row & 2047;
        ushort4 ov;
        ov.x = f2bf(acc[i][j][0] + bv);
        ov.y = f2bf(acc[i][j][1] + bv);
        ov.z = f2bf(acc[i][j][2] + bv);
        ov.w = f2bf(acc[i][j][3] + bv);
        *(ushort4*)(&Vt[(size_t)((bb * 16 + hh) * 64 + dd) * NN + nl]) = ov;
      } else {
        const int ldc = (MODE == 2) ? 2048 : N;
#pragma unroll
        for (int ri = 0; ri < 4; ++ri) {
          float v = acc[i][j][ri] + bv;
          ((ushort*)Cv)[(size_t)(row + ri) * ldc + col] = f2bf(v);
        }
      }
    }
  }
}

// ---------------- proj GEMM (float out), 64x128 tile, 2 blocks/CU ----------------
__global__ __launch_bounds__(256) void gemm_proj(const ushort* __restrict__ A,
                                                 const ushort* __restrict__ Bt,
                                                 const float* __restrict__ bias,
                                                 float* __restrict__ C, int M, int N, int K) {
  __shared__ ushort As[64 * 32];
  __shared__ ushort Bs[128 * 32];
  const int tid = threadIdx.x;
  const int wid = tid >> 6, lane = tid & 63;
  const int c = lane & 15, g = lane >> 4;
  const int wn = wid * 32;
  const int m0 = blockIdx.y * 64, n0 = blockIdx.x * 128;
  f32x4 acc[4][2] = {};
  for (int k0 = 0; k0 < K; k0 += 32) {
    __syncthreads();
#pragma unroll
    for (int it = 0; it < 3; ++it) {
      int G = tid + it * 256;
      if (G < 256) {
        int row = G >> 2, sl = G & 3;
        GLOAD_LDS16(A + (size_t)(m0 + row) * K + k0 + sl * 8, &As[G * 8]);
      } else {
        int GB = G - 256;
        int row = GB >> 2, sl = GB & 3;
        GLOAD_LDS16(Bt + (size_t)(n0 + row) * K + k0 + sl * 8, &Bs[GB * 8]);
      }
    }
    __syncthreads();
    bf16x8 af[4], bfr[2];
#pragma unroll
    for (int i = 0; i < 4; ++i) af[i] = *(const bf16x8*)(&As[(i * 16 + c) * 32 + g * 8]);
#pragma unroll
    for (int j = 0; j < 2; ++j)
      bfr[j] = *(const bf16x8*)(&Bs[(wn + j * 16 + c) * 32 + g * 8]);
#pragma unroll
    for (int i = 0; i < 4; ++i)
#pragma unroll
      for (int j = 0; j < 2; ++j)
        acc[i][j] = __builtin_amdgcn_mfma_f32_16x16x32_bf16(af[i], bfr[j], acc[i][j], 0, 0, 0);
  }
#pragma unroll
  for (int i = 0; i < 4; ++i) {
#pragma unroll
    for (int j = 0; j < 2; ++j) {
      const int col = n0 + wn + j * 16 + c;
      const float bv = bias[col];
      const int row = m0 + i * 16 + g * 4;
#pragma unroll
      for (int ri = 0; ri < 4; ++ri)
        C[(size_t)(row + ri) * N + col] = acc[i][j][ri] + bv;
    }
  }
}

// ---------------- causal flash attention, split-KV for heavy q-blocks --------------
// grid (32 bh, 24): y<8 -> qb=y full range, direct output. y>=8 -> qb=8+(y-8)/2,
// half=(y-8)&1: half0 covers kv tiles [0,qb+1) (no diagonal), half1 [qb+1, 2qb+2)
// (diagonal). Split blocks write unnormalized partials (O bf16, m/l fp32, log2 dom)
// for attn_combine. Per-block work uniform 9..17 steps -> fixes makespan imbalance.
__global__ __launch_bounds__(512) void attn_fwd(const ushort* __restrict__ QK,
                                                const ushort* __restrict__ Vt,
                                                ushort* __restrict__ O,
                                                ushort* __restrict__ partO,
                                                float* __restrict__ partML) {
  const int bh = blockIdx.x;
  const int b = bh >> 4, h = bh & 15;
  const int y = blockIdx.y;
  int qb, t_lo, t_hi, half;
  bool split;
  if (y < 8) {
    qb = y; t_lo = 0; t_hi = 2 * qb + 2; half = 0; split = false;
  } else {
    int u = y - 8;
    qb = 8 + (u >> 1); half = u & 1; split = true;
    int mid = qb + 1;
    t_lo = half ? mid : 0;
    t_hi = half ? (2 * qb + 2) : mid;
  }
  const int tid = threadIdx.x;
  const int wid = tid >> 6, lane = tid & 63;
  const int c = lane & 15, g = lane >> 4;
  const int q0 = qb * 128 + wid * 16;
  const ushort* Qb = QK + (size_t)b * NN * 2048 + (size_t)h * HDD;
  const ushort* Kb = Qb + 1024;
  const ushort* Vb = Vt + (size_t)bh * HDD * NN;

  __shared__ ushort Ks[2][64 * 64];  // linear; content XOR-swizzled via source addr
  __shared__ ushort Vs[2][64 * 64];

  // Q fragment, pre-scaled by 0.125 * log2(e)
  const float SC = 0.18033688011112042f;
  bf16x8 qf[2];
  {
    const ushort* qrow = Qb + (size_t)(q0 + c) * 2048 + g * 8;
    qf[0] = *(const bf16x8*)(qrow);
    qf[1] = *(const bf16x8*)(qrow + 32);
#pragma unroll
    for (int r = 0; r < 2; ++r)
#pragma unroll
      for (int e = 0; e < 8; ++e) qf[r][e] = (short)f2bf(bf2f((ushort)qf[r][e]) * SC);
  }

  f32x4 oacc[4] = {};  // O^T[d = 16db + 4g + i][q0+c]
  float m = 0.f, lsum = 0.f;  // m in log2 domain, per q-row (c), uniform over g
  const int q_abs = q0 + c;
  const int tdiag = 2 * qb + (wid >> 2);  // this wave's diagonal tile (only if t_hi==2qb+2)

#define STAGE_TILE(kv0, bufi)                                                   \
  do {                                                                          \
    int u = tid;                                                                \
    int row = u >> 3, sl = u & 7;                                               \
    int ksl = (sl ^ (row & 7)) * 8;                                             \
    GLOAD_LDS16(Kb + (size_t)((kv0) + row) * 2048 + ksl, &Ks[bufi][u * 8]);     \
    GLOAD_LDS16(Vb + (size_t)row * NN + (kv0) + ksl, &Vs[bufi][u * 8]);         \
  } while (0)

  STAGE_TILE(t_lo * 64, 0);
  __syncthreads();
  int cur = 0;

  for (int t = t_lo; t < t_hi; ++t) {
    if (t + 1 < t_hi) STAGE_TILE((t + 1) * 64, cur ^ 1);  // prefetch overlaps compute

    if (t <= tdiag) {  // wave-uniform activity gate
      f32x4 s[4] = {};
#pragma unroll
      for (int f = 0; f < 4; ++f) {
        int krow = f * 16 + c;
#pragma unroll
        for (int dc = 0; dc < 2; ++dc) {
          int slot = (dc * 4 + g) ^ (krow & 7);
          bf16x8 kf = *(const bf16x8*)(&Ks[cur][krow * 64 + slot * 8]);
          s[f] = __builtin_amdgcn_mfma_f32_16x16x32_bf16(kf, qf[dc], s[f], 0, 0, 0);
        }
      }

      float pmax = -INFINITY;
      if (t == tdiag) {
        const int kv0 = t * 64;
#pragma unroll
        for (int f = 0; f < 4; ++f)
#pragma unroll
          for (int i = 0; i < 4; ++i) {
            if (kv0 + f * 16 + g * 4 + i > q_abs) s[f][i] = -INFINITY;
            pmax = fmaxf(pmax, s[f][i]);
          }
      } else {
#pragma unroll
        for (int f = 0; f < 4; ++f)
#pragma unroll
          for (int i = 0; i < 4; ++i) pmax = fmaxf(pmax, s[f][i]);
      }

      if (t == t_lo) {
        float pr = fmaxf(pmax, __shfl_xor(pmax, 16));
        pr = fmaxf(pr, __shfl_xor(pr, 32));
        m = pr;
      } else if (!__all(pmax <= m + 8.f)) {
        float pr = fmaxf(pmax, __shfl_xor(pmax, 16));
        pr = fmaxf(pr, __shfl_xor(pr, 32));
        float mnew = fmaxf(m, pr);
        float corr = exp2_raw(m - mnew);
        lsum *= corr;
#pragma unroll
        for (int db = 0; db < 4; ++db) {
          oacc[db][0] *= corr; oacc[db][1] *= corr;
          oacc[db][2] *= corr; oacc[db][3] *= corr;
        }
        m = mnew;
      }

      float psum = 0.f;
#pragma unroll
      for (int f = 0; f < 4; ++f)
#pragma unroll
        for (int i = 0; i < 4; ++i) {
          float p = exp2_raw(s[f][i] - m);
          s[f][i] = p;
          psum += p;
        }
      lsum += psum;

#pragma unroll
      for (int f = 0; f < 4; ++f) {
        bf16x4 pb;
        pb[0] = (short)f2bf(s[f][0]);
        pb[1] = (short)f2bf(s[f][1]);
        pb[2] = (short)f2bf(s[f][2]);
        pb[3] = (short)f2bf(s[f][3]);
        const int slot = f * 2 + (g >> 1);
#pragma unroll
        for (int db = 0; db < 4; ++db) {
          int d = db * 16 + c;
          bf16x4 vf =
              *(const bf16x4*)(&Vs[cur][d * 64 + ((slot ^ (d & 7)) * 8) + (g & 1) * 4]);
          oacc[db] = __builtin_amdgcn_mfma_f32_16x16x16bf16_1k(vf, pb, oacc[db], 0, 0, 0);
        }
      }
    }
    __syncthreads();
    cur ^= 1;
  }

  // per-q-row l (reduce over g)
  lsum += __shfl_xor(lsum, 16);
  lsum += __shfl_xor(lsum, 32);

  if (!split) {
    float invl = 1.f / lsum;
    ushort* orow = O + (size_t)(b * NN + q0 + c) * DDIM + h * HDD;
#pragma unroll
    for (int db = 0; db < 4; ++db) {
      ushort4 ov;
      ov.x = f2bf(oacc[db][0] * invl);
      ov.y = f2bf(oacc[db][1] * invl);
      ov.z = f2bf(oacc[db][2] * invl);
      ov.w = f2bf(oacc[db][3] * invl);
      *(ushort4*)(&orow[db * 16 + g * 4]) = ov;
    }
  } else {
    const int e = (((bh << 3) + (qb - 8)) << 1) + half;
    const int ql = wid * 16 + c;  // local q-row 0..127
    if (g == 0) {
      partML[(size_t)e * 256 + ql] = m;
      partML[(size_t)e * 256 + 128 + ql] = lsum;
    }
    ushort* po = partO + (size_t)e * 8192 + ql * 64;
#pragma unroll
    for (int db = 0; db < 4; ++db) {
      ushort4 ov;
      ov.x = f2bf(oacc[db][0]);
      ov.y = f2bf(oacc[db][1]);
      ov.z = f2bf(oacc[db][2]);
      ov.w = f2bf(oacc[db][3]);
      *(ushort4*)(&po[db * 16 + g * 4]) = ov;
    }
  }
}

// ---------------- merge split-KV partials (qb 8..15) ----------------
// grid (32 bh, 8). 256 thr: q = tid&127, dh = tid>>7 (32 d each).
__global__ __launch_bounds__(256) void attn_combine(const ushort* __restrict__ partO,
                                                    const float* __restrict__ partML,
                                                    ushort* __restrict__ O) {
  const int bh = blockIdx.x, qb8 = blockIdx.y;
  const int b = bh >> 4, h = bh & 15;
  const int tid = threadIdx.x;
  const int q = tid & 127, dh = tid >> 7;
  const int e0 = (((bh << 3) + qb8) << 1), e1 = e0 + 1;
  const float ma = partML[(size_t)e0 * 256 + q], la = partML[(size_t)e0 * 256 + 128 + q];
  const float mb = partML[(size_t)e1 * 256 + q], lb = partML[(size_t)e1 * 256 + 128 + q];
  const float mm = fmaxf(ma, mb);
  const float wa = exp2_raw(ma - mm), wb = exp2_raw(mb - mm);
  const float inv = 1.f / (la * wa + lb * wb);
  const ushort* pa = partO + (size_t)e0 * 8192 + q * 64 + dh * 32;
  const ushort* pc = partO + (size_t)e1 * 8192 + q * 64 + dh * 32;
  const int qg = (8 + qb8) * 128 + q;
  ushort* out = O + (size_t)(b * NN + qg) * DDIM + h * HDD + dh * 32;
#pragma unroll
  for (int j0 = 0; j0 < 32; j0 += 8) {
    bf16x8 va = *(const bf16x8*)(pa + j0);
    bf16x8 vb = *(const bf16x8*)(pc + j0);
    bf16x8 vo;
#pragma unroll
    for (int e = 0; e < 8; ++e)
      vo[e] = (short)f2bf((bf2f((ushort)va[e]) * wa + bf2f((ushort)vb[e]) * wb) * inv);
    *(bf16x8*)(out + j0) = vo;
  }
}

extern "C" void kernel_launch(void* const* d_in, const int* in_sizes, int n_in,
                              void* d_out, int out_size, void* d_ws, size_t ws_size,
                              hipStream_t stream) {
  const float* hidden = (const float*)d_in[0];  // [B,N,D]
  const float* W_attn = (const float*)d_in[1];  // [D,3D]
  const float* b_attn = (const float*)d_in[2];  // [3D]
  const float* W_proj = (const float*)d_in[3];  // [D,D]
  const float* b_proj = (const float*)d_in[4];  // [D]

  char* ws = (char*)d_ws;
  ushort* hbf  = (ushort*)(ws);                       // 8 MB  hidden bf16 (dead after qkv)
  ushort* WaT  = (ushort*)(ws + (size_t)(8 << 20));   // 6 MB  W_attn^T (dead after qkv)
  ushort* WpT  = (ushort*)(ws + (size_t)(14 << 20));  // 2 MB  W_proj^T
  ushort* qk   = (ushort*)(ws + (size_t)(16 << 20));  // 16 MB Q|K bf16 [4096][2048]
  ushort* vt   = (ushort*)(ws + (size_t)(32 << 20));  // 8 MB  V^T bf16 [32][64][2048]
  ushort* aout = (ushort*)(ws + (size_t)(40 << 20));  // 8 MB  attn out bf16 [4096][1024]
  // split-KV partials reuse the dead hbf/WaT region during attention:
  ushort* partO  = (ushort*)(ws);                     // 8 MB  [512 entries][128q][64d] bf16
  float*  partML = (float*)(ws + (size_t)(8 << 20));  // 0.5MB [512][m128|l128] fp32

  prep<<<2048 + 3072 + 1024, 256, 0, stream>>>(hidden, W_attn, W_proj, hbf, WaT, WpT);
  gemm_bt<2><<<dim3(24, 32), 256, 0, stream>>>(hbf, WaT, b_attn, qk, vt, 4096, 3072, 1024);
  attn_fwd<<<dim3(32, 24), 512, 0, stream>>>(qk, vt, aout, partO, partML);
  attn_combine<<<dim3(32, 8), 256, 0, stream>>>(partO, partML, aout);
  gemm_proj<<<dim3(8, 64), 256, 0, stream>>>(aout, WpT, b_proj, (float*)d_out, 4096, 1024, 1024);
}